// Round 13
// baseline (498.134 us; speedup 1.0000x reference)
//
#include <hip/hip_runtime.h>
#include <hip/hip_bf16.h>

typedef unsigned short ushort_t;
typedef __attribute__((ext_vector_type(8))) short short8;
typedef __attribute__((ext_vector_type(4))) float f32x4;

// ---------------- problem constants ----------------
// conv1: x[128,1,28,28]*w[256,1,9,9] s1 -> h1t[128,20,20,256] (NHWC bf16)
// caps1: implicit GEMM M=4608 N=256 K=81*256, split-K ci-quarter.
//        128x64 tile, 8 waves; A via LDS dbuf+swizzle; B DIRECT from L2.
// u_hat: bf16 [b][q][p][16]; routing = separate sv x3 / agree x2 (r10).

// ---------------- ws layout (bytes) ----------------
#define OFFB_H1T  0u           // 26,214,400
#define OFFB_WT   26214400u    // 10,616,832
#define OFFB_PART 36831232u    // 18,874,368
#define OFFB_H2   55705600u    //  4,718,592
#define OFFB_UH   60424192u    // 47,185,920
#define OFFB_BIJ  107610112u   //  5,898,240
#define OFFB_C    113508352u   //  5,898,240
#define OFFB_V    119406592u   //     81,920
#define OFFB_F1   119488512u   //    262,144
#define OFFB_F2   119750656u   //    524,288
#define OFFB_W1T  120274944u   //     82,944  -> total ~120.4 MB

__device__ __forceinline__ ushort_t f2bf(float f) {
  union { float f; unsigned int u; } c; c.f = f;
  unsigned int r = (c.u + 0x7FFFu + ((c.u >> 16) & 1u)) >> 16;
  return (ushort_t)r;
}
__device__ __forceinline__ float bf2f(ushort_t u) {
  union { unsigned int i; float f; } c; c.i = ((unsigned int)u) << 16;
  return c.f;
}

// ========== conv1 weight transpose: w[co][kk] -> w1t[kk][co] f32 ==========
__global__ __launch_bounds__(256) void w1t_kernel(
    const float* __restrict__ w, float* __restrict__ w1t) {
  int kk = blockIdx.x;
  int co = threadIdx.x;
  w1t[kk * 256 + co] = w[co * 81 + kk];
}

// ================= conv1 + relu -> NHWC bf16 =================
__global__ __launch_bounds__(256) void conv1_kernel(
    const float* __restrict__ x, const float* __restrict__ w1t,
    const float* __restrict__ bias, ushort_t* __restrict__ h1t) {
  int blk = blockIdx.x;
  int b = blk / 20, oy = blk % 20;
  int co = threadIdx.x;
  __shared__ float xs[252];
  for (int l = co; l < 252; l += 256)
    xs[l] = x[b * 784 + (oy + l / 28) * 28 + (l % 28)];
  __syncthreads();
  float bs = bias[co];
  float acc[20];
#pragma unroll
  for (int i = 0; i < 20; ++i) acc[i] = bs;
  for (int ky = 0; ky < 9; ++ky) {
    float xr[28];
#pragma unroll
    for (int i = 0; i < 28; ++i) xr[i] = xs[ky * 28 + i];
    float wk[9];
#pragma unroll
    for (int kx = 0; kx < 9; ++kx) wk[kx] = w1t[(ky * 9 + kx) * 256 + co];
#pragma unroll
    for (int kx = 0; kx < 9; ++kx)
#pragma unroll
      for (int ox = 0; ox < 20; ++ox) acc[ox] += wk[kx] * xr[ox + kx];
  }
  int xb = (b * 20 + oy) * 20;
#pragma unroll
  for (int ox = 0; ox < 20; ++ox)
    h1t[(xb + ox) * 256 + co] = f2bf(fmaxf(acc[ox], 0.f));
}

// ========== caps1 weight reorder: w[co][ci][kk] -> wt[kk][co][ci] bf16 =====
__global__ __launch_bounds__(256) void wreorder_kernel(
    const float* __restrict__ w, ushort_t* __restrict__ wt) {
  int co = blockIdx.x;
  __shared__ ushort_t wl[256 * 82];
  int t = threadIdx.x;
  const float* src = w + (size_t)co * 20736;
  for (int e = t; e < 20736; e += 256) {
    int ci = e / 81, kk = e - ci * 81;
    wl[ci * 82 + kk] = f2bf(src[e]);
  }
  __syncthreads();
  for (int kk = 0; kk < 81; ++kk)
    wt[((size_t)kk * 256 + co) * 256 + t] = wl[t * 82 + kk];
}

// ====== caps1 v3: 128x64 tile, 8 waves; A in LDS, B direct from L2 ======
// 576 blocks (4 chunks x 36 m x 4 n), XCD-bijective. LDS = 32KB (A only).
__global__ __launch_bounds__(512) void caps1_gemm(
    const ushort_t* __restrict__ h1t, const ushort_t* __restrict__ wt,
    float* __restrict__ part) {
  int lb = (blockIdx.x & 7) * 72 + (blockIdx.x >> 3);
  int chunk = lb / 144;
  int tile = lb - chunk * 144;
  int gm0 = (tile >> 2) * 128;
  int gn0 = (tile & 3) * 64;
  int ci0 = chunk << 6;
  int t = threadIdx.x;
  int wave = t >> 6, lane = t & 63;
  int wm = (wave >> 1) * 32, wn = (wave & 1) * 32;
  int lr = lane & 15, lg = lane >> 4;

  __shared__ __align__(16) ushort_t As[2][128 * 64];  // 16KB x2 (A only)

  // A staging (r10 verified): row ar = t>>2, seg = t&3
  int ar = t >> 2, aseg = t & 3;
  int am = gm0 + ar;
  int ab_ = am / 36, pos = am - ab_ * 36;
  int oy = pos / 6, ox = pos - oy * 6;
  const ushort_t* arow =
      h1t + ((ab_ * 20 + 2 * oy) * 20 + 2 * ox) * 256 + ci0 + aseg * 16;
  int ax = ar & 7;
  int ast0 = ar * 64 + (((aseg << 1) | 0) ^ ax) * 8;
  int ast1 = ar * 64 + (((aseg << 1) | 1) ^ ax) * 8;

  // A fragment read slots (swizzled)
  int lx = lr & 7;
  int sl0 = ((0 * 4 + lg) ^ lx) * 8;
  int sl1 = ((1 * 4 + lg) ^ lx) * 8;

  // B direct-from-global fragment pointers (linear addresses, no swizzle)
  const ushort_t* bptr[2];
#pragma unroll
  for (int nf = 0; nf < 2; ++nf)
    bptr[nf] = wt + (size_t)(gn0 + wn + nf * 16 + lr) * 256 + ci0 + lg * 8;

  f32x4 acc[2][2];
#pragma unroll
  for (int i = 0; i < 2; ++i)
#pragma unroll
    for (int j = 0; j < 2; ++j)
#pragma unroll
      for (int e = 0; e < 4; ++e) acc[i][j][e] = 0.f;

  float4 ra0, ra1;
  short8 bcur[2][2], bnext[2][2];
  // prologue: stage A(kk=0), load B frags(kk=0)
  ra0 = *(const float4*)(arow);
  ra1 = *(const float4*)(arow + 8);
  *(float4*)&As[0][ast0] = ra0;
  *(float4*)&As[0][ast1] = ra1;
#pragma unroll
  for (int nf = 0; nf < 2; ++nf)
#pragma unroll
    for (int kh = 0; kh < 2; ++kh)
      bcur[nf][kh] = *(const short8*)(bptr[nf] + kh * 32);
  __syncthreads();

  int buf = 0;
  for (int kk = 0; kk < 81; ++kk) {
    int nxt = kk + 1;
    if (nxt < 81) {
      int ky = nxt / 9, kx = nxt - ky * 9;
      const ushort_t* ap = arow + (ky * 20 + kx) * 256;
      ra0 = *(const float4*)(ap);
      ra1 = *(const float4*)(ap + 8);
      size_t boff = (size_t)nxt * 65536;
#pragma unroll
      for (int nf = 0; nf < 2; ++nf)
#pragma unroll
        for (int kh = 0; kh < 2; ++kh)
          bnext[nf][kh] = *(const short8*)(bptr[nf] + boff + kh * 32);
    }
    short8 af[2][2];
#pragma unroll
    for (int mf = 0; mf < 2; ++mf) {
      int ra = (wm + mf * 16 + lr) * 64;
      af[mf][0] = *(const short8*)&As[buf][ra + sl0];
      af[mf][1] = *(const short8*)&As[buf][ra + sl1];
    }
#pragma unroll
    for (int kh = 0; kh < 2; ++kh)
#pragma unroll
      for (int mf = 0; mf < 2; ++mf)
#pragma unroll
        for (int nf = 0; nf < 2; ++nf)
          acc[mf][nf] = __builtin_amdgcn_mfma_f32_16x16x32_bf16(
              af[mf][kh], bcur[nf][kh], acc[mf][nf], 0, 0, 0);
    __syncthreads();
    if (nxt < 81) {
      int nb = buf ^ 1;
      *(float4*)&As[nb][ast0] = ra0;
      *(float4*)&As[nb][ast1] = ra1;
      __syncthreads();
#pragma unroll
      for (int nf = 0; nf < 2; ++nf)
#pragma unroll
        for (int kh = 0; kh < 2; ++kh)
          bcur[nf][kh] = bnext[nf][kh];
    }
    buf ^= 1;
  }

  float* pbase = part + (size_t)chunk * 4608 * 256;
#pragma unroll
  for (int mf = 0; mf < 2; ++mf)
#pragma unroll
    for (int nf = 0; nf < 2; ++nf) {
      int nn = gn0 + wn + nf * 16 + lr;
#pragma unroll
      for (int reg = 0; reg < 4; ++reg) {
        int mm = gm0 + wm + mf * 16 + lg * 4 + reg;
        pbase[(size_t)mm * 256 + nn] = acc[mf][nf][reg];
      }
    }
}

// ==== reduce (float4): h2[m][n] = relu(sum_c part[c][m][n] + bias[n]) =====
__global__ __launch_bounds__(256) void reduce_kernel(
    const float* __restrict__ part, const float* __restrict__ bias,
    float* __restrict__ h2) {
  int tid = blockIdx.x * 256 + threadIdx.x;
  size_t o = (size_t)tid * 4;
  int n0 = (int)(o & 255);
  float4 s0 = *(const float4*)&part[o];
  float4 s1 = *(const float4*)&part[o + (size_t)4608 * 256];
  float4 s2 = *(const float4*)&part[o + (size_t)2 * 4608 * 256];
  float4 s3 = *(const float4*)&part[o + (size_t)3 * 4608 * 256];
  float4 bv = *(const float4*)&bias[n0];
  float4 r;
  r.x = fmaxf(s0.x + s1.x + s2.x + s3.x + bv.x, 0.f);
  r.y = fmaxf(s0.y + s1.y + s2.y + s3.y + bv.y, 0.f);
  r.z = fmaxf(s0.z + s1.z + s2.z + s3.z + bv.z, 0.f);
  r.w = fmaxf(s0.w + s1.w + s2.w + s3.w + bv.w, 0.f);
  *(float4*)&h2[o] = r;
}

// ================= u_hat materialize (W-local, LDS-staged) ============
__global__ __launch_bounds__(256) void uhat_kernel(
    const float* __restrict__ h2, const float* __restrict__ W,
    ushort_t* __restrict__ uh) {
  int blk = blockIdx.x;
  int bh = blk & 1;
  int qpc = blk >> 1;
  int q = qpc / 72;
  int pc = qpc - q * 72;
  int p0 = pc * 16;
  int b0 = bh * 64;
  __shared__ float Wl[16][132];
  __shared__ float xl[64][16][9];
  int t = threadIdx.x;
#pragma unroll
  for (int it = 0; it < 2; ++it) {
    int idx = t * 2 + it;
    int row = idx >> 5;
    int c4 = idx & 31;
    float4 vv = *(reinterpret_cast<const float4*>(
        &W[(size_t)((p0 + row) * 10 + q) * 128]) + c4);
    Wl[row][c4 * 4 + 0] = vv.x;
    Wl[row][c4 * 4 + 1] = vv.y;
    Wl[row][c4 * 4 + 2] = vv.z;
    Wl[row][c4 * 4 + 3] = vv.w;
  }
  for (int j = 0; j < 32; ++j) {
    int e = t + 256 * j;
    int b_l = e >> 7;
    int rem = e & 127;
    int i = rem >> 3, n = rem & 7;
    int f = (p0 + i) * 80 + q * 8 + n;
    xl[b_l][i][n] = h2[((size_t)(b0 + b_l) * 36 + (f % 36)) * 256 + (f / 360)];
  }
  __syncthreads();
  int p_l = t & 15;
  int b_ll = t >> 4;
  const float* wr = &Wl[p_l][0];
#pragma unroll
  for (int k = 0; k < 4; ++k) {
    int b_l = b_ll + 16 * k;
    float xv[8];
#pragma unroll
    for (int n = 0; n < 8; ++n) xv[n] = xl[b_l][p_l][n];
    short8 o0, o1;
#pragma unroll
    for (int a = 0; a < 8; ++a) {
      float ue = 0.f, uo = 0.f;
#pragma unroll
      for (int n = 0; n < 8; ++n) {
        ue += wr[a * 16 + n] * xv[n];
        uo += wr[a * 16 + 8 + n] * xv[n];
      }
      if (a < 4) { o0[2 * a] = (short)f2bf(ue); o0[2 * a + 1] = (short)f2bf(uo); }
      else { o1[2 * (a - 4)] = (short)f2bf(ue); o1[2 * (a - 4) + 1] = (short)f2bf(uo); }
    }
    size_t dst = ((size_t)((b0 + b_l) * 10 + q) * 1152 + p0 + p_l) * 16;
    *(short8*)&uh[dst] = o0;
    *(short8*)&uh[dst + 8] = o1;
  }
}

// ================= sv: weighted sum + squash (4 waves) =================
template <int MODE>
__global__ __launch_bounds__(256) void sv_kernel(
    const ushort_t* __restrict__ uh, const float* __restrict__ cbuf,
    const float* __restrict__ caps_bias, float* __restrict__ v,
    float* __restrict__ out) {
  int bq = blockIdx.x;
  int q = bq % 10;
  int t = threadIdx.x;
  const ushort_t* ub = &uh[(size_t)bq * 1152 * 16];
  const float* cb = &cbuf[(size_t)bq * 1152];
  float s[16];
#pragma unroll
  for (int m = 0; m < 16; ++m) s[m] = 0.f;
  for (int p = t; p < 1152; p += 256) {
    short8 u0 = *(const short8*)&ub[p * 16];
    short8 u1 = *(const short8*)&ub[p * 16 + 8];
    float c = (MODE == 0) ? 0.1f : cb[p];
#pragma unroll
    for (int m = 0; m < 8; ++m) s[m] += c * bf2f((ushort_t)u0[m]);
#pragma unroll
    for (int m = 0; m < 8; ++m) s[8 + m] += c * bf2f((ushort_t)u1[m]);
  }
  __shared__ float red[4][16];
#pragma unroll
  for (int m = 0; m < 16; ++m) {
    float val = s[m];
#pragma unroll
    for (int off = 32; off > 0; off >>= 1) val += __shfl_down(val, off);
    if ((t & 63) == 0) red[t >> 6][m] = val;
  }
  __syncthreads();
  if (t == 0) {
    float sq = 0.f;
    float sj[16];
#pragma unroll
    for (int m = 0; m < 16; ++m) {
      sj[m] = red[0][m] + red[1][m] + red[2][m] + red[3][m] +
              caps_bias[q * 16 + m];
      sq += sj[m] * sj[m];
    }
    float coef = (sq / (1.f + sq)) * rsqrtf(sq + 1e-9f);
    float vl2 = 0.f;
#pragma unroll
    for (int m = 0; m < 16; ++m) {
      float vv = coef * sj[m];
      v[bq * 16 + m] = vv;
      vl2 += vv * vv;
    }
    if (MODE == 2) out[bq] = sqrtf(vl2 + 1e-9f);
  }
}

// ======== agree: d=u.v, bij update, fused softmax -> c ========
template <bool FIRST>
__global__ __launch_bounds__(256) void agree_kernel(
    const ushort_t* __restrict__ uh, const float* __restrict__ v,
    float* __restrict__ bij, float* __restrict__ cbuf) {
  int tid = blockIdx.x * 256 + threadIdx.x;
  int b = tid / 1152;
  int p = tid - b * 1152;
  float br[10];
  float* bp = &bij[(size_t)tid * 10];
#pragma unroll
  for (int q = 0; q < 10; ++q) {
    const ushort_t* ub = &uh[(size_t)((b * 10 + q) * 1152 + p) * 16];
    short8 u0 = *(const short8*)ub;
    short8 u1 = *(const short8*)(ub + 8);
    const float4* v4 = reinterpret_cast<const float4*>(&v[(b * 10 + q) * 16]);
    float4 b0 = v4[0], b1 = v4[1], b2 = v4[2], b3 = v4[3];
    float d = bf2f((ushort_t)u0[0]) * b0.x + bf2f((ushort_t)u0[1]) * b0.y
            + bf2f((ushort_t)u0[2]) * b0.z + bf2f((ushort_t)u0[3]) * b0.w
            + bf2f((ushort_t)u0[4]) * b1.x + bf2f((ushort_t)u0[5]) * b1.y
            + bf2f((ushort_t)u0[6]) * b1.z + bf2f((ushort_t)u0[7]) * b1.w
            + bf2f((ushort_t)u1[0]) * b2.x + bf2f((ushort_t)u1[1]) * b2.y
            + bf2f((ushort_t)u1[2]) * b2.z + bf2f((ushort_t)u1[3]) * b2.w
            + bf2f((ushort_t)u1[4]) * b3.x + bf2f((ushort_t)u1[5]) * b3.y
            + bf2f((ushort_t)u1[6]) * b3.z + bf2f((ushort_t)u1[7]) * b3.w;
    br[q] = (FIRST ? 0.f : bp[q]) + d;
  }
  float mx = br[0];
#pragma unroll
  for (int q = 1; q < 10; ++q) mx = fmaxf(mx, br[q]);
  float den = 0.f;
  float ex[10];
#pragma unroll
  for (int q = 0; q < 10; ++q) { ex[q] = __expf(br[q] - mx); den += ex[q]; }
  float inv = 1.f / den;
#pragma unroll
  for (int q = 0; q < 10; ++q) {
    bp[q] = br[q];
    cbuf[(size_t)(b * 10 + q) * 1152 + p] = ex[q] * inv;
  }
}

// ================= fc1: masked_v + fc1 =================
__global__ __launch_bounds__(128) void fc1_kernel(
    const float* __restrict__ v, const float* __restrict__ y,
    const float* __restrict__ fc1_w, const float* __restrict__ fc1_b,
    float* __restrict__ f1g) {
  int b = blockIdx.x, t = threadIdx.x;
  __shared__ float mv[16];
  if (t < 16) {
    const float* vb = &v[b * 160];
    float a = 0.f;
#pragma unroll
    for (int tt = 0; tt < 10; ++tt) a += vb[t * 10 + tt] * y[b * 10 + tt];
    mv[t] = a;
  }
  __syncthreads();
  for (int o = t; o < 512; o += 128) {
    const float4* wr = reinterpret_cast<const float4*>(&fc1_w[o * 16]);
    float4 w0 = wr[0], w1 = wr[1], w2 = wr[2], w3 = wr[3];
    f1g[b * 512 + o] = fc1_b[o]
        + mv[0] * w0.x + mv[1] * w0.y + mv[2] * w0.z + mv[3] * w0.w
        + mv[4] * w1.x + mv[5] * w1.y + mv[6] * w1.z + mv[7] * w1.w
        + mv[8] * w2.x + mv[9] * w2.y + mv[10] * w2.z + mv[11] * w2.w
        + mv[12] * w3.x + mv[13] * w3.y + mv[14] * w3.z + mv[15] * w3.w;
  }
}

// ================= fc2 =================
__global__ __launch_bounds__(256) void fc2_kernel(
    const float* __restrict__ f1g, const float* __restrict__ fc2_w,
    const float* __restrict__ fc2_b, float* __restrict__ f2g) {
  int b = blockIdx.x >> 2;
  int o = (blockIdx.x & 3) * 256 + threadIdx.x;
  __shared__ float f1[512];
  for (int l = threadIdx.x; l < 512; l += 256) f1[l] = f1g[b * 512 + l];
  __syncthreads();
  const float4* wr = reinterpret_cast<const float4*>(&fc2_w[o * 512]);
  float a = fc2_b[o];
#pragma unroll 4
  for (int k4 = 0; k4 < 128; ++k4) {
    float4 w4 = wr[k4];
    a += f1[4 * k4] * w4.x + f1[4 * k4 + 1] * w4.y + f1[4 * k4 + 2] * w4.z +
         f1[4 * k4 + 3] * w4.w;
  }
  f2g[b * 1024 + o] = a;
}

// ================= fc3 + sigmoid =================
__global__ __launch_bounds__(256) void fc3_kernel(
    const float* __restrict__ f2g, const float* __restrict__ fc3_w,
    const float* __restrict__ fc3_b, float* __restrict__ out) {
  int b = blockIdx.x >> 2;
  int oc = (blockIdx.x & 3) * 196;
  __shared__ float f2[1024];
  for (int l = threadIdx.x; l < 1024; l += 256) f2[l] = f2g[b * 1024 + l];
  __syncthreads();
  if (threadIdx.x >= 196) return;
  int o = oc + threadIdx.x;
  const float4* wr = reinterpret_cast<const float4*>(&fc3_w[o * 1024]);
  float a = fc3_b[o];
#pragma unroll 4
  for (int k4 = 0; k4 < 256; ++k4) {
    float4 w4 = wr[k4];
    a += f2[4 * k4] * w4.x + f2[4 * k4 + 1] * w4.y + f2[4 * k4 + 2] * w4.z +
         f2[4 * k4 + 3] * w4.w;
  }
  out[1280 + b * 784 + o] = 1.f / (1.f + __expf(-a));
}

extern "C" void kernel_launch(void* const* d_in, const int* in_sizes, int n_in,
                              void* d_out, int out_size, void* d_ws, size_t ws_size,
                              hipStream_t stream) {
  const float* x       = (const float*)d_in[0];
  const float* y       = (const float*)d_in[1];
  const float* conv1_w = (const float*)d_in[2];
  const float* conv1_b = (const float*)d_in[3];
  const float* caps1_w = (const float*)d_in[4];
  const float* caps1_b = (const float*)d_in[5];
  const float* W       = (const float*)d_in[6];
  const float* cbias   = (const float*)d_in[7];
  const float* fc1_w   = (const float*)d_in[8];
  const float* fc1_b   = (const float*)d_in[9];
  const float* fc2_w   = (const float*)d_in[10];
  const float* fc2_b   = (const float*)d_in[11];
  const float* fc3_w   = (const float*)d_in[12];
  const float* fc3_b   = (const float*)d_in[13];
  float* out = (float*)d_out;

  char* wsb = (char*)d_ws;
  ushort_t* h1t  = (ushort_t*)(wsb + OFFB_H1T);
  ushort_t* wt   = (ushort_t*)(wsb + OFFB_WT);
  float*    part = (float*)(wsb + OFFB_PART);
  float*    h2   = (float*)(wsb + OFFB_H2);
  ushort_t* uh   = (ushort_t*)(wsb + OFFB_UH);
  float*    bij  = (float*)(wsb + OFFB_BIJ);
  float*    c    = (float*)(wsb + OFFB_C);
  float*    v    = (float*)(wsb + OFFB_V);
  float*    f1   = (float*)(wsb + OFFB_F1);
  float*    f2   = (float*)(wsb + OFFB_F2);
  float*    w1t  = (float*)(wsb + OFFB_W1T);

  w1t_kernel<<<81, 256, 0, stream>>>(conv1_w, w1t);
  conv1_kernel<<<2560, 256, 0, stream>>>(x, w1t, conv1_b, h1t);
  wreorder_kernel<<<256, 256, 0, stream>>>(caps1_w, wt);
  caps1_gemm<<<576, 512, 0, stream>>>(h1t, wt, part);
  reduce_kernel<<<1152, 256, 0, stream>>>(part, caps1_b, h2);
  uhat_kernel<<<1440, 256, 0, stream>>>(h2, W, uh);

  sv_kernel<0><<<1280, 256, 0, stream>>>(uh, c, cbias, v, out);
  agree_kernel<true><<<576, 256, 0, stream>>>(uh, v, bij, c);
  sv_kernel<1><<<1280, 256, 0, stream>>>(uh, c, cbias, v, out);
  agree_kernel<false><<<576, 256, 0, stream>>>(uh, v, bij, c);
  sv_kernel<2><<<1280, 256, 0, stream>>>(uh, c, cbias, v, out);

  fc1_kernel<<<128, 128, 0, stream>>>(v, y, fc1_w, fc1_b, f1);
  fc2_kernel<<<512, 256, 0, stream>>>(f1, fc2_w, fc2_b, f2);
  fc3_kernel<<<512, 256, 0, stream>>>(f2, fc3_w, fc3_b, out);
}

// Round 14
// 430.187 us; speedup vs baseline: 1.1579x; 1.1579x over previous
//
#include <hip/hip_runtime.h>
#include <hip/hip_bf16.h>

typedef unsigned short ushort_t;
typedef __attribute__((ext_vector_type(8))) short short8;
typedef __attribute__((ext_vector_type(4))) float f32x4;

// ---------------- problem constants ----------------
// conv1: x[128,1,28,28]*w[256,1,9,9] s1 -> h1t[128,20,20,256] (NHWC bf16)
// caps1: implicit GEMM M=4608 N=256 K=81*256, split-K ci-quarter (r10 kernel)
// uhat: reads part directly (reduce+bias+relu folded in) -> uh bf16 [b][q][p][16]
// routing: separate sv x3 / agree x2 (r10 verified). Output f32.

// ---------------- ws layout (bytes) ----------------
#define OFFB_H1T  0u           // 26,214,400
#define OFFB_WT   26214400u    // 10,616,832
#define OFFB_PART 36831232u    // 18,874,368
#define OFFB_UH   60424192u    // 47,185,920
#define OFFB_BIJ  107610112u   //  5,898,240
#define OFFB_C    113508352u   //  5,898,240
#define OFFB_V    119406592u   //     81,920
#define OFFB_F2   119750656u   //    524,288
#define OFFB_W1T  120274944u   //     82,944  -> total ~120.4 MB

#define PCH ((size_t)4608 * 256)   // part chunk stride (floats)

__device__ __forceinline__ ushort_t f2bf(float f) {
  union { float f; unsigned int u; } c; c.f = f;
  unsigned int r = (c.u + 0x7FFFu + ((c.u >> 16) & 1u)) >> 16;
  return (ushort_t)r;
}
__device__ __forceinline__ float bf2f(ushort_t u) {
  union { unsigned int i; float f; } c; c.i = ((unsigned int)u) << 16;
  return c.f;
}

// ========== conv1 weight transpose: w[co][kk] -> w1t[kk][co] f32 ==========
__global__ __launch_bounds__(256) void w1t_kernel(
    const float* __restrict__ w, float* __restrict__ w1t) {
  int kk = blockIdx.x;
  int co = threadIdx.x;
  w1t[kk * 256 + co] = w[co * 81 + kk];
}

// ================= conv1 + relu -> NHWC bf16 =================
__global__ __launch_bounds__(256) void conv1_kernel(
    const float* __restrict__ x, const float* __restrict__ w1t,
    const float* __restrict__ bias, ushort_t* __restrict__ h1t) {
  int blk = blockIdx.x;
  int b = blk / 20, oy = blk % 20;
  int co = threadIdx.x;
  __shared__ float xs[252];
  for (int l = co; l < 252; l += 256)
    xs[l] = x[b * 784 + (oy + l / 28) * 28 + (l % 28)];
  __syncthreads();
  float bs = bias[co];
  float acc[20];
#pragma unroll
  for (int i = 0; i < 20; ++i) acc[i] = bs;
  for (int ky = 0; ky < 9; ++ky) {
    float xr[28];
#pragma unroll
    for (int i = 0; i < 28; ++i) xr[i] = xs[ky * 28 + i];
    float wk[9];
#pragma unroll
    for (int kx = 0; kx < 9; ++kx) wk[kx] = w1t[(ky * 9 + kx) * 256 + co];
#pragma unroll
    for (int kx = 0; kx < 9; ++kx)
#pragma unroll
      for (int ox = 0; ox < 20; ++ox) acc[ox] += wk[kx] * xr[ox + kx];
  }
  int xb = (b * 20 + oy) * 20;
#pragma unroll
  for (int ox = 0; ox < 20; ++ox)
    h1t[(xb + ox) * 256 + co] = f2bf(fmaxf(acc[ox], 0.f));
}

// ========== caps1 weight reorder: w[co][ci][kk] -> wt[kk][co][ci] bf16 =====
__global__ __launch_bounds__(256) void wreorder_kernel(
    const float* __restrict__ w, ushort_t* __restrict__ wt) {
  int co = blockIdx.x;
  __shared__ ushort_t wl[256 * 82];
  int t = threadIdx.x;
  const float* src = w + (size_t)co * 20736;
  for (int e = t; e < 20736; e += 256) {
    int ci = e / 81, kk = e - ci * 81;
    wl[ci * 82 + kk] = f2bf(src[e]);
  }
  __syncthreads();
  for (int kk = 0; kk < 81; ++kk)
    wt[((size_t)kk * 256 + co) * 256 + t] = wl[t * 82 + kk];
}

// ====== caps1 implicit GEMM (r10 verified): 128x64 tile, 8 waves ======
__global__ __launch_bounds__(512) void caps1_gemm(
    const ushort_t* __restrict__ h1t, const ushort_t* __restrict__ wt,
    float* __restrict__ part) {
  int lb = (blockIdx.x & 7) * 72 + (blockIdx.x >> 3);
  int chunk = lb / 144;
  int tile = lb - chunk * 144;
  int gm0 = (tile >> 2) * 128;
  int gn0 = (tile & 3) * 64;
  int ci0 = chunk << 6;
  int t = threadIdx.x;
  int wave = t >> 6, lane = t & 63;
  int wm = (wave >> 1) * 32, wn = (wave & 1) * 32;
  int lr = lane & 15, lg = lane >> 4;

  __shared__ __align__(16) ushort_t As[2][128 * 64];
  __shared__ __align__(16) ushort_t Bs[2][64 * 64];

  int ar = t >> 2, aseg = t & 3;
  int am = gm0 + ar;
  int ab_ = am / 36, pos = am - ab_ * 36;
  int oy = pos / 6, ox = pos - oy * 6;
  const ushort_t* arow =
      h1t + ((ab_ * 20 + 2 * oy) * 20 + 2 * ox) * 256 + ci0 + aseg * 16;
  int ax = ar & 7;
  int ast0 = ar * 64 + (((aseg << 1) | 0) ^ ax) * 8;
  int ast1 = ar * 64 + (((aseg << 1) | 1) ^ ax) * 8;
  int brr = t >> 3, bseg = t & 7;
  const ushort_t* brow = wt + (size_t)(gn0 + brr) * 256 + ci0 + bseg * 8;
  int bst = brr * 64 + (bseg ^ (brr & 7)) * 8;

  int lx = lr & 7;
  int sl0 = ((0 * 4 + lg) ^ lx) * 8;
  int sl1 = ((1 * 4 + lg) ^ lx) * 8;

  f32x4 acc[2][2];
#pragma unroll
  for (int i = 0; i < 2; ++i)
#pragma unroll
    for (int j = 0; j < 2; ++j)
#pragma unroll
      for (int e = 0; e < 4; ++e) acc[i][j][e] = 0.f;

  float4 ra0, ra1, rb0;
  ra0 = *(const float4*)(arow);
  ra1 = *(const float4*)(arow + 8);
  rb0 = *(const float4*)(brow);
  *(float4*)&As[0][ast0] = ra0;
  *(float4*)&As[0][ast1] = ra1;
  *(float4*)&Bs[0][bst] = rb0;
  __syncthreads();

  int buf = 0;
  for (int kk = 0; kk < 81; ++kk) {
    int nxt = kk + 1;
    if (nxt < 81) {
      int ky = nxt / 9, kx = nxt - ky * 9;
      const ushort_t* ap = arow + (ky * 20 + kx) * 256;
      ra0 = *(const float4*)(ap);
      ra1 = *(const float4*)(ap + 8);
      rb0 = *(const float4*)(brow + (size_t)nxt * 65536);
    }
    short8 af[2][2], bfr[2][2];
#pragma unroll
    for (int mf = 0; mf < 2; ++mf) {
      int ra = (wm + mf * 16 + lr) * 64;
      af[mf][0] = *(const short8*)&As[buf][ra + sl0];
      af[mf][1] = *(const short8*)&As[buf][ra + sl1];
    }
#pragma unroll
    for (int nf = 0; nf < 2; ++nf) {
      int rb = (wn + nf * 16 + lr) * 64;
      bfr[nf][0] = *(const short8*)&Bs[buf][rb + sl0];
      bfr[nf][1] = *(const short8*)&Bs[buf][rb + sl1];
    }
#pragma unroll
    for (int kh = 0; kh < 2; ++kh)
#pragma unroll
      for (int mf = 0; mf < 2; ++mf)
#pragma unroll
        for (int nf = 0; nf < 2; ++nf)
          acc[mf][nf] = __builtin_amdgcn_mfma_f32_16x16x32_bf16(
              af[mf][kh], bfr[nf][kh], acc[mf][nf], 0, 0, 0);
    __syncthreads();
    if (nxt < 81) {
      int nb = buf ^ 1;
      *(float4*)&As[nb][ast0] = ra0;
      *(float4*)&As[nb][ast1] = ra1;
      *(float4*)&Bs[nb][bst] = rb0;
      __syncthreads();
    }
    buf ^= 1;
  }

  float* pbase = part + (size_t)chunk * PCH;
#pragma unroll
  for (int mf = 0; mf < 2; ++mf)
#pragma unroll
    for (int nf = 0; nf < 2; ++nf) {
      int nn = gn0 + wn + nf * 16 + lr;
#pragma unroll
      for (int reg = 0; reg < 4; ++reg) {
        int mm = gm0 + wm + mf * 16 + lg * 4 + reg;
        pbase[(size_t)mm * 256 + nn] = acc[mf][nf][reg];
      }
    }
}

// ==== u_hat materialize; reduce+bias+relu folded (h2 never materialized) ===
// grid = ((q*72 + pc)*2 + bh), 1440 blocks, 256 threads.
__global__ __launch_bounds__(256) void uhat_kernel(
    const float* __restrict__ part, const float* __restrict__ cbias1,
    const float* __restrict__ W, ushort_t* __restrict__ uh) {
  int blk = blockIdx.x;
  int bh = blk & 1;
  int qpc = blk >> 1;
  int q = qpc / 72;
  int pc = qpc - q * 72;
  int p0 = pc * 16;
  int b0 = bh * 64;
  __shared__ float Wl[16][132];
  __shared__ float xl[64][16][9];
  int t = threadIdx.x;
#pragma unroll
  for (int it = 0; it < 2; ++it) {
    int idx = t * 2 + it;
    int row = idx >> 5;
    int c4 = idx & 31;
    float4 vv = *(reinterpret_cast<const float4*>(
        &W[(size_t)((p0 + row) * 10 + q) * 128]) + c4);
    Wl[row][c4 * 4 + 0] = vv.x;
    Wl[row][c4 * 4 + 1] = vv.y;
    Wl[row][c4 * 4 + 2] = vv.z;
    Wl[row][c4 * 4 + 3] = vv.w;
  }
  for (int j = 0; j < 32; ++j) {
    int e = t + 256 * j;
    int b_l = e >> 7;
    int rem = e & 127;
    int i = rem >> 3, nn = rem & 7;
    int f = (p0 + i) * 80 + q * 8 + nn;
    int m = (b0 + b_l) * 36 + (f % 36);
    int co = f / 360;
    size_t o = (size_t)m * 256 + co;
    float s = part[o] + part[o + PCH] + part[o + 2 * PCH] + part[o + 3 * PCH];
    xl[b_l][i][nn] = fmaxf(s + cbias1[co], 0.f);
  }
  __syncthreads();
  int p_l = t & 15;
  int b_ll = t >> 4;
  const float* wr = &Wl[p_l][0];
#pragma unroll
  for (int k = 0; k < 4; ++k) {
    int b_l = b_ll + 16 * k;
    float xv[8];
#pragma unroll
    for (int n = 0; n < 8; ++n) xv[n] = xl[b_l][p_l][n];
    short8 o0, o1;
#pragma unroll
    for (int a = 0; a < 8; ++a) {
      float ue = 0.f, uo = 0.f;
#pragma unroll
      for (int n = 0; n < 8; ++n) {
        ue += wr[a * 16 + n] * xv[n];
        uo += wr[a * 16 + 8 + n] * xv[n];
      }
      if (a < 4) { o0[2 * a] = (short)f2bf(ue); o0[2 * a + 1] = (short)f2bf(uo); }
      else { o1[2 * (a - 4)] = (short)f2bf(ue); o1[2 * (a - 4) + 1] = (short)f2bf(uo); }
    }
    size_t dst = ((size_t)((b0 + b_l) * 10 + q) * 1152 + p0 + p_l) * 16;
    *(short8*)&uh[dst] = o0;
    *(short8*)&uh[dst + 8] = o1;
  }
}

// ================= sv: weighted sum + squash (4 waves) =================
template <int MODE>
__global__ __launch_bounds__(256) void sv_kernel(
    const ushort_t* __restrict__ uh, const float* __restrict__ cbuf,
    const float* __restrict__ caps_bias, float* __restrict__ v,
    float* __restrict__ out) {
  int bq = blockIdx.x;
  int q = bq % 10;
  int t = threadIdx.x;
  const ushort_t* ub = &uh[(size_t)bq * 1152 * 16];
  const float* cb = &cbuf[(size_t)bq * 1152];
  float s[16];
#pragma unroll
  for (int m = 0; m < 16; ++m) s[m] = 0.f;
  for (int p = t; p < 1152; p += 256) {
    short8 u0 = *(const short8*)&ub[p * 16];
    short8 u1 = *(const short8*)&ub[p * 16 + 8];
    float c = (MODE == 0) ? 0.1f : cb[p];
#pragma unroll
    for (int m = 0; m < 8; ++m) s[m] += c * bf2f((ushort_t)u0[m]);
#pragma unroll
    for (int m = 0; m < 8; ++m) s[8 + m] += c * bf2f((ushort_t)u1[m]);
  }
  __shared__ float red[4][16];
#pragma unroll
  for (int m = 0; m < 16; ++m) {
    float val = s[m];
#pragma unroll
    for (int off = 32; off > 0; off >>= 1) val += __shfl_down(val, off);
    if ((t & 63) == 0) red[t >> 6][m] = val;
  }
  __syncthreads();
  if (t == 0) {
    float sq = 0.f;
    float sj[16];
#pragma unroll
    for (int m = 0; m < 16; ++m) {
      sj[m] = red[0][m] + red[1][m] + red[2][m] + red[3][m] +
              caps_bias[q * 16 + m];
      sq += sj[m] * sj[m];
    }
    float coef = (sq / (1.f + sq)) * rsqrtf(sq + 1e-9f);
    float vl2 = 0.f;
#pragma unroll
    for (int m = 0; m < 16; ++m) {
      float vv = coef * sj[m];
      v[bq * 16 + m] = vv;
      vl2 += vv * vv;
    }
    if (MODE == 2) out[bq] = sqrtf(vl2 + 1e-9f);
  }
}

// ======== agree: d=u.v, bij update, fused softmax -> c ========
template <bool FIRST>
__global__ __launch_bounds__(256) void agree_kernel(
    const ushort_t* __restrict__ uh, const float* __restrict__ v,
    float* __restrict__ bij, float* __restrict__ cbuf) {
  int tid = blockIdx.x * 256 + threadIdx.x;
  int b = tid / 1152;
  int p = tid - b * 1152;
  float br[10];
  float* bp = &bij[(size_t)tid * 10];
#pragma unroll
  for (int q = 0; q < 10; ++q) {
    const ushort_t* ub = &uh[(size_t)((b * 10 + q) * 1152 + p) * 16];
    short8 u0 = *(const short8*)ub;
    short8 u1 = *(const short8*)(ub + 8);
    const float4* v4 = reinterpret_cast<const float4*>(&v[(b * 10 + q) * 16]);
    float4 b0 = v4[0], b1 = v4[1], b2 = v4[2], b3 = v4[3];
    float d = bf2f((ushort_t)u0[0]) * b0.x + bf2f((ushort_t)u0[1]) * b0.y
            + bf2f((ushort_t)u0[2]) * b0.z + bf2f((ushort_t)u0[3]) * b0.w
            + bf2f((ushort_t)u0[4]) * b1.x + bf2f((ushort_t)u0[5]) * b1.y
            + bf2f((ushort_t)u0[6]) * b1.z + bf2f((ushort_t)u0[7]) * b1.w
            + bf2f((ushort_t)u1[0]) * b2.x + bf2f((ushort_t)u1[1]) * b2.y
            + bf2f((ushort_t)u1[2]) * b2.z + bf2f((ushort_t)u1[3]) * b2.w
            + bf2f((ushort_t)u1[4]) * b3.x + bf2f((ushort_t)u1[5]) * b3.y
            + bf2f((ushort_t)u1[6]) * b3.z + bf2f((ushort_t)u1[7]) * b3.w;
    br[q] = (FIRST ? 0.f : bp[q]) + d;
  }
  float mx = br[0];
#pragma unroll
  for (int q = 1; q < 10; ++q) mx = fmaxf(mx, br[q]);
  float den = 0.f;
  float ex[10];
#pragma unroll
  for (int q = 0; q < 10; ++q) { ex[q] = __expf(br[q] - mx); den += ex[q]; }
  float inv = 1.f / den;
#pragma unroll
  for (int q = 0; q < 10; ++q) {
    bp[q] = br[q];
    cbuf[(size_t)(b * 10 + q) * 1152 + p] = ex[q] * inv;
  }
}

// ============ fc1+fc2 fused: mv + f1 in LDS, 256 f2 outputs =============
// grid 512: b = blk>>2, o-chunk = blk&3. mv/f1 recomputed per chunk (cheap).
__global__ __launch_bounds__(256) void fc12_kernel(
    const float* __restrict__ v, const float* __restrict__ y,
    const float* __restrict__ fc1_w, const float* __restrict__ fc1_b,
    const float* __restrict__ fc2_w, const float* __restrict__ fc2_b,
    float* __restrict__ f2g) {
  int b = blockIdx.x >> 2;
  int t = threadIdx.x;
  __shared__ float mv[16];
  __shared__ float f1[512];
  if (t < 16) {
    const float* vb = &v[b * 160];
    float a = 0.f;
#pragma unroll
    for (int tt = 0; tt < 10; ++tt) a += vb[t * 10 + tt] * y[b * 10 + tt];
    mv[t] = a;
  }
  __syncthreads();
  for (int o = t; o < 512; o += 256) {
    const float4* wr = reinterpret_cast<const float4*>(&fc1_w[o * 16]);
    float4 w0 = wr[0], w1 = wr[1], w2 = wr[2], w3 = wr[3];
    f1[o] = fc1_b[o]
        + mv[0] * w0.x + mv[1] * w0.y + mv[2] * w0.z + mv[3] * w0.w
        + mv[4] * w1.x + mv[5] * w1.y + mv[6] * w1.z + mv[7] * w1.w
        + mv[8] * w2.x + mv[9] * w2.y + mv[10] * w2.z + mv[11] * w2.w
        + mv[12] * w3.x + mv[13] * w3.y + mv[14] * w3.z + mv[15] * w3.w;
  }
  __syncthreads();
  int o = (blockIdx.x & 3) * 256 + t;
  const float4* wr = reinterpret_cast<const float4*>(&fc2_w[o * 512]);
  float a = fc2_b[o];
#pragma unroll 4
  for (int k4 = 0; k4 < 128; ++k4) {
    float4 w4 = wr[k4];
    a += f1[4 * k4] * w4.x + f1[4 * k4 + 1] * w4.y + f1[4 * k4 + 2] * w4.z +
         f1[4 * k4 + 3] * w4.w;
  }
  f2g[b * 1024 + o] = a;
}

// ================= fc3 + sigmoid =================
__global__ __launch_bounds__(256) void fc3_kernel(
    const float* __restrict__ f2g, const float* __restrict__ fc3_w,
    const float* __restrict__ fc3_b, float* __restrict__ out) {
  int b = blockIdx.x >> 2;
  int oc = (blockIdx.x & 3) * 196;
  __shared__ float f2[1024];
  for (int l = threadIdx.x; l < 1024; l += 256) f2[l] = f2g[b * 1024 + l];
  __syncthreads();
  if (threadIdx.x >= 196) return;
  int o = oc + threadIdx.x;
  const float4* wr = reinterpret_cast<const float4*>(&fc3_w[o * 1024]);
  float a = fc3_b[o];
#pragma unroll 4
  for (int k4 = 0; k4 < 256; ++k4) {
    float4 w4 = wr[k4];
    a += f2[4 * k4] * w4.x + f2[4 * k4 + 1] * w4.y + f2[4 * k4 + 2] * w4.z +
         f2[4 * k4 + 3] * w4.w;
  }
  out[1280 + b * 784 + o] = 1.f / (1.f + __expf(-a));
}

extern "C" void kernel_launch(void* const* d_in, const int* in_sizes, int n_in,
                              void* d_out, int out_size, void* d_ws, size_t ws_size,
                              hipStream_t stream) {
  const float* x       = (const float*)d_in[0];
  const float* y       = (const float*)d_in[1];
  const float* conv1_w = (const float*)d_in[2];
  const float* conv1_b = (const float*)d_in[3];
  const float* caps1_w = (const float*)d_in[4];
  const float* caps1_b = (const float*)d_in[5];
  const float* W       = (const float*)d_in[6];
  const float* cbias   = (const float*)d_in[7];
  const float* fc1_w   = (const float*)d_in[8];
  const float* fc1_b   = (const float*)d_in[9];
  const float* fc2_w   = (const float*)d_in[10];
  const float* fc2_b   = (const float*)d_in[11];
  const float* fc3_w   = (const float*)d_in[12];
  const float* fc3_b   = (const float*)d_in[13];
  float* out = (float*)d_out;

  char* wsb = (char*)d_ws;
  ushort_t* h1t  = (ushort_t*)(wsb + OFFB_H1T);
  ushort_t* wt   = (ushort_t*)(wsb + OFFB_WT);
  float*    part = (float*)(wsb + OFFB_PART);
  ushort_t* uh   = (ushort_t*)(wsb + OFFB_UH);
  float*    bij  = (float*)(wsb + OFFB_BIJ);
  float*    c    = (float*)(wsb + OFFB_C);
  float*    v    = (float*)(wsb + OFFB_V);
  float*    f2   = (float*)(wsb + OFFB_F2);
  float*    w1t  = (float*)(wsb + OFFB_W1T);

  w1t_kernel<<<81, 256, 0, stream>>>(conv1_w, w1t);
  conv1_kernel<<<2560, 256, 0, stream>>>(x, w1t, conv1_b, h1t);
  wreorder_kernel<<<256, 256, 0, stream>>>(caps1_w, wt);
  caps1_gemm<<<576, 512, 0, stream>>>(h1t, wt, part);
  uhat_kernel<<<1440, 256, 0, stream>>>(part, caps1_b, W, uh);

  sv_kernel<0><<<1280, 256, 0, stream>>>(uh, c, cbias, v, out);
  agree_kernel<true><<<576, 256, 0, stream>>>(uh, v, bij, c);
  sv_kernel<1><<<1280, 256, 0, stream>>>(uh, c, cbias, v, out);
  agree_kernel<false><<<576, 256, 0, stream>>>(uh, v, bij, c);
  sv_kernel<2><<<1280, 256, 0, stream>>>(uh, c, cbias, v, out);

  fc12_kernel<<<512, 256, 0, stream>>>(v, y, fc1_w, fc1_b, fc2_w, fc2_b, f2);
  fc3_kernel<<<512, 256, 0, stream>>>(f2, fc3_w, fc3_b, out);
}

// Round 15
// 328.330 us; speedup vs baseline: 1.5172x; 1.3102x over previous
//
#include <hip/hip_runtime.h>
#include <hip/hip_bf16.h>

typedef unsigned short ushort_t;
typedef __attribute__((ext_vector_type(8))) short short8;
typedef __attribute__((ext_vector_type(4))) float f32x4;

// ---------------- problem constants ----------------
// conv1: x[128,1,28,28]*w[256,1,9,9] s1 -> h1t[128,20,20,256] (NHWC bf16)
// caps1: implicit GEMM M=4608 N=256 K=81*256, split-K ci-quarter (r10 kernel)
// reduce: part -> h2[m][n] f32 (float4). uhat reads compact h2 (L3-resident).
// routing: separate sv x3 / agree x2. fc1+fc2 fused. Output f32.

// ---------------- ws layout (bytes) ----------------
#define OFFB_H1T  0u           // 26,214,400
#define OFFB_WT   26214400u    // 10,616,832
#define OFFB_PART 36831232u    // 18,874,368
#define OFFB_H2   55705600u    //  4,718,592
#define OFFB_UH   60424192u    // 47,185,920
#define OFFB_BIJ  107610112u   //  5,898,240
#define OFFB_C    113508352u   //  5,898,240
#define OFFB_V    119406592u   //     81,920
#define OFFB_F2   119750656u   //    524,288
#define OFFB_W1T  120274944u   //     82,944  -> total ~120.4 MB

#define PCH ((size_t)4608 * 256)

__device__ __forceinline__ ushort_t f2bf(float f) {
  union { float f; unsigned int u; } c; c.f = f;
  unsigned int r = (c.u + 0x7FFFu + ((c.u >> 16) & 1u)) >> 16;
  return (ushort_t)r;
}
__device__ __forceinline__ float bf2f(ushort_t u) {
  union { unsigned int i; float f; } c; c.i = ((unsigned int)u) << 16;
  return c.f;
}

// ========== conv1 weight transpose: w[co][kk] -> w1t[kk][co] f32 ==========
__global__ __launch_bounds__(256) void w1t_kernel(
    const float* __restrict__ w, float* __restrict__ w1t) {
  int kk = blockIdx.x;
  int co = threadIdx.x;
  w1t[kk * 256 + co] = w[co * 81 + kk];
}

// ================= conv1 + relu -> NHWC bf16 =================
__global__ __launch_bounds__(256) void conv1_kernel(
    const float* __restrict__ x, const float* __restrict__ w1t,
    const float* __restrict__ bias, ushort_t* __restrict__ h1t) {
  int blk = blockIdx.x;
  int b = blk / 20, oy = blk % 20;
  int co = threadIdx.x;
  __shared__ float xs[252];
  for (int l = co; l < 252; l += 256)
    xs[l] = x[b * 784 + (oy + l / 28) * 28 + (l % 28)];
  __syncthreads();
  float bs = bias[co];
  float acc[20];
#pragma unroll
  for (int i = 0; i < 20; ++i) acc[i] = bs;
  for (int ky = 0; ky < 9; ++ky) {
    float xr[28];
#pragma unroll
    for (int i = 0; i < 28; ++i) xr[i] = xs[ky * 28 + i];
    float wk[9];
#pragma unroll
    for (int kx = 0; kx < 9; ++kx) wk[kx] = w1t[(ky * 9 + kx) * 256 + co];
#pragma unroll
    for (int kx = 0; kx < 9; ++kx)
#pragma unroll
      for (int ox = 0; ox < 20; ++ox) acc[ox] += wk[kx] * xr[ox + kx];
  }
  int xb = (b * 20 + oy) * 20;
#pragma unroll
  for (int ox = 0; ox < 20; ++ox)
    h1t[(xb + ox) * 256 + co] = f2bf(fmaxf(acc[ox], 0.f));
}

// ========== caps1 weight reorder: w[co][ci][kk] -> wt[kk][co][ci] bf16 =====
__global__ __launch_bounds__(256) void wreorder_kernel(
    const float* __restrict__ w, ushort_t* __restrict__ wt) {
  int co = blockIdx.x;
  __shared__ ushort_t wl[256 * 82];
  int t = threadIdx.x;
  const float* src = w + (size_t)co * 20736;
  for (int e = t; e < 20736; e += 256) {
    int ci = e / 81, kk = e - ci * 81;
    wl[ci * 82 + kk] = f2bf(src[e]);
  }
  __syncthreads();
  for (int kk = 0; kk < 81; ++kk)
    wt[((size_t)kk * 256 + co) * 256 + t] = wl[t * 82 + kk];
}

// ====== caps1 implicit GEMM (r10 verified): 128x64 tile, 8 waves ======
__global__ __launch_bounds__(512) void caps1_gemm(
    const ushort_t* __restrict__ h1t, const ushort_t* __restrict__ wt,
    float* __restrict__ part) {
  int lb = (blockIdx.x & 7) * 72 + (blockIdx.x >> 3);
  int chunk = lb / 144;
  int tile = lb - chunk * 144;
  int gm0 = (tile >> 2) * 128;
  int gn0 = (tile & 3) * 64;
  int ci0 = chunk << 6;
  int t = threadIdx.x;
  int wave = t >> 6, lane = t & 63;
  int wm = (wave >> 1) * 32, wn = (wave & 1) * 32;
  int lr = lane & 15, lg = lane >> 4;

  __shared__ __align__(16) ushort_t As[2][128 * 64];
  __shared__ __align__(16) ushort_t Bs[2][64 * 64];

  int ar = t >> 2, aseg = t & 3;
  int am = gm0 + ar;
  int ab_ = am / 36, pos = am - ab_ * 36;
  int oy = pos / 6, ox = pos - oy * 6;
  const ushort_t* arow =
      h1t + ((ab_ * 20 + 2 * oy) * 20 + 2 * ox) * 256 + ci0 + aseg * 16;
  int ax = ar & 7;
  int ast0 = ar * 64 + (((aseg << 1) | 0) ^ ax) * 8;
  int ast1 = ar * 64 + (((aseg << 1) | 1) ^ ax) * 8;
  int brr = t >> 3, bseg = t & 7;
  const ushort_t* brow = wt + (size_t)(gn0 + brr) * 256 + ci0 + bseg * 8;
  int bst = brr * 64 + (bseg ^ (brr & 7)) * 8;

  int lx = lr & 7;
  int sl0 = ((0 * 4 + lg) ^ lx) * 8;
  int sl1 = ((1 * 4 + lg) ^ lx) * 8;

  f32x4 acc[2][2];
#pragma unroll
  for (int i = 0; i < 2; ++i)
#pragma unroll
    for (int j = 0; j < 2; ++j)
#pragma unroll
      for (int e = 0; e < 4; ++e) acc[i][j][e] = 0.f;

  float4 ra0, ra1, rb0;
  ra0 = *(const float4*)(arow);
  ra1 = *(const float4*)(arow + 8);
  rb0 = *(const float4*)(brow);
  *(float4*)&As[0][ast0] = ra0;
  *(float4*)&As[0][ast1] = ra1;
  *(float4*)&Bs[0][bst] = rb0;
  __syncthreads();

  int buf = 0;
  for (int kk = 0; kk < 81; ++kk) {
    int nxt = kk + 1;
    if (nxt < 81) {
      int ky = nxt / 9, kx = nxt - ky * 9;
      const ushort_t* ap = arow + (ky * 20 + kx) * 256;
      ra0 = *(const float4*)(ap);
      ra1 = *(const float4*)(ap + 8);
      rb0 = *(const float4*)(brow + (size_t)nxt * 65536);
    }
    short8 af[2][2], bfr[2][2];
#pragma unroll
    for (int mf = 0; mf < 2; ++mf) {
      int ra = (wm + mf * 16 + lr) * 64;
      af[mf][0] = *(const short8*)&As[buf][ra + sl0];
      af[mf][1] = *(const short8*)&As[buf][ra + sl1];
    }
#pragma unroll
    for (int nf = 0; nf < 2; ++nf) {
      int rb = (wn + nf * 16 + lr) * 64;
      bfr[nf][0] = *(const short8*)&Bs[buf][rb + sl0];
      bfr[nf][1] = *(const short8*)&Bs[buf][rb + sl1];
    }
#pragma unroll
    for (int kh = 0; kh < 2; ++kh)
#pragma unroll
      for (int mf = 0; mf < 2; ++mf)
#pragma unroll
        for (int nf = 0; nf < 2; ++nf)
          acc[mf][nf] = __builtin_amdgcn_mfma_f32_16x16x32_bf16(
              af[mf][kh], bfr[nf][kh], acc[mf][nf], 0, 0, 0);
    __syncthreads();
    if (nxt < 81) {
      int nb = buf ^ 1;
      *(float4*)&As[nb][ast0] = ra0;
      *(float4*)&As[nb][ast1] = ra1;
      *(float4*)&Bs[nb][bst] = rb0;
      __syncthreads();
    }
    buf ^= 1;
  }

  float* pbase = part + (size_t)chunk * PCH;
#pragma unroll
  for (int mf = 0; mf < 2; ++mf)
#pragma unroll
    for (int nf = 0; nf < 2; ++nf) {
      int nn = gn0 + wn + nf * 16 + lr;
#pragma unroll
      for (int reg = 0; reg < 4; ++reg) {
        int mm = gm0 + wm + mf * 16 + lg * 4 + reg;
        pbase[(size_t)mm * 256 + nn] = acc[mf][nf][reg];
      }
    }
}

// ==== reduce (float4): h2[m][n] = relu(sum_c part[c][m][n] + bias[n]) =====
__global__ __launch_bounds__(256) void reduce_kernel(
    const float* __restrict__ part, const float* __restrict__ bias,
    float* __restrict__ h2) {
  int tid = blockIdx.x * 256 + threadIdx.x;
  size_t o = (size_t)tid * 4;
  int n0 = (int)(o & 255);
  float4 s0 = *(const float4*)&part[o];
  float4 s1 = *(const float4*)&part[o + PCH];
  float4 s2 = *(const float4*)&part[o + 2 * PCH];
  float4 s3 = *(const float4*)&part[o + 3 * PCH];
  float4 bv = *(const float4*)&bias[n0];
  float4 r;
  r.x = fmaxf(s0.x + s1.x + s2.x + s3.x + bv.x, 0.f);
  r.y = fmaxf(s0.y + s1.y + s2.y + s3.y + bv.y, 0.f);
  r.z = fmaxf(s0.z + s1.z + s2.z + s3.z + bv.z, 0.f);
  r.w = fmaxf(s0.w + s1.w + s2.w + s3.w + bv.w, 0.f);
  *(float4*)&h2[o] = r;
}

// ================= u_hat materialize (h2-based, verified r7) ============
__global__ __launch_bounds__(256) void uhat_kernel(
    const float* __restrict__ h2, const float* __restrict__ W,
    ushort_t* __restrict__ uh) {
  int blk = blockIdx.x;
  int bh = blk & 1;
  int qpc = blk >> 1;
  int q = qpc / 72;
  int pc = qpc - q * 72;
  int p0 = pc * 16;
  int b0 = bh * 64;
  __shared__ float Wl[16][132];
  __shared__ float xl[64][16][9];
  int t = threadIdx.x;
#pragma unroll
  for (int it = 0; it < 2; ++it) {
    int idx = t * 2 + it;
    int row = idx >> 5;
    int c4 = idx & 31;
    float4 vv = *(reinterpret_cast<const float4*>(
        &W[(size_t)((p0 + row) * 10 + q) * 128]) + c4);
    Wl[row][c4 * 4 + 0] = vv.x;
    Wl[row][c4 * 4 + 1] = vv.y;
    Wl[row][c4 * 4 + 2] = vv.z;
    Wl[row][c4 * 4 + 3] = vv.w;
  }
  for (int j = 0; j < 32; ++j) {
    int e = t + 256 * j;
    int b_l = e >> 7;
    int rem = e & 127;
    int i = rem >> 3, n = rem & 7;
    int f = (p0 + i) * 80 + q * 8 + n;
    xl[b_l][i][n] = h2[((size_t)(b0 + b_l) * 36 + (f % 36)) * 256 + (f / 360)];
  }
  __syncthreads();
  int p_l = t & 15;
  int b_ll = t >> 4;
  const float* wr = &Wl[p_l][0];
#pragma unroll
  for (int k = 0; k < 4; ++k) {
    int b_l = b_ll + 16 * k;
    float xv[8];
#pragma unroll
    for (int n = 0; n < 8; ++n) xv[n] = xl[b_l][p_l][n];
    short8 o0, o1;
#pragma unroll
    for (int a = 0; a < 8; ++a) {
      float ue = 0.f, uo = 0.f;
#pragma unroll
      for (int n = 0; n < 8; ++n) {
        ue += wr[a * 16 + n] * xv[n];
        uo += wr[a * 16 + 8 + n] * xv[n];
      }
      if (a < 4) { o0[2 * a] = (short)f2bf(ue); o0[2 * a + 1] = (short)f2bf(uo); }
      else { o1[2 * (a - 4)] = (short)f2bf(ue); o1[2 * (a - 4) + 1] = (short)f2bf(uo); }
    }
    size_t dst = ((size_t)((b0 + b_l) * 10 + q) * 1152 + p0 + p_l) * 16;
    *(short8*)&uh[dst] = o0;
    *(short8*)&uh[dst + 8] = o1;
  }
}

// ================= sv: weighted sum + squash (4 waves) =================
template <int MODE>
__global__ __launch_bounds__(256) void sv_kernel(
    const ushort_t* __restrict__ uh, const float* __restrict__ cbuf,
    const float* __restrict__ caps_bias, float* __restrict__ v,
    float* __restrict__ out) {
  int bq = blockIdx.x;
  int q = bq % 10;
  int t = threadIdx.x;
  const ushort_t* ub = &uh[(size_t)bq * 1152 * 16];
  const float* cb = &cbuf[(size_t)bq * 1152];
  float s[16];
#pragma unroll
  for (int m = 0; m < 16; ++m) s[m] = 0.f;
  for (int p = t; p < 1152; p += 256) {
    short8 u0 = *(const short8*)&ub[p * 16];
    short8 u1 = *(const short8*)&ub[p * 16 + 8];
    float c = (MODE == 0) ? 0.1f : cb[p];
#pragma unroll
    for (int m = 0; m < 8; ++m) s[m] += c * bf2f((ushort_t)u0[m]);
#pragma unroll
    for (int m = 0; m < 8; ++m) s[8 + m] += c * bf2f((ushort_t)u1[m]);
  }
  __shared__ float red[4][16];
#pragma unroll
  for (int m = 0; m < 16; ++m) {
    float val = s[m];
#pragma unroll
    for (int off = 32; off > 0; off >>= 1) val += __shfl_down(val, off);
    if ((t & 63) == 0) red[t >> 6][m] = val;
  }
  __syncthreads();
  if (t == 0) {
    float sq = 0.f;
    float sj[16];
#pragma unroll
    for (int m = 0; m < 16; ++m) {
      sj[m] = red[0][m] + red[1][m] + red[2][m] + red[3][m] +
              caps_bias[q * 16 + m];
      sq += sj[m] * sj[m];
    }
    float coef = (sq / (1.f + sq)) * rsqrtf(sq + 1e-9f);
    float vl2 = 0.f;
#pragma unroll
    for (int m = 0; m < 16; ++m) {
      float vv = coef * sj[m];
      v[bq * 16 + m] = vv;
      vl2 += vv * vv;
    }
    if (MODE == 2) out[bq] = sqrtf(vl2 + 1e-9f);
  }
}

// ======== agree: d=u.v, bij update, fused softmax -> c ========
template <bool FIRST>
__global__ __launch_bounds__(256) void agree_kernel(
    const ushort_t* __restrict__ uh, const float* __restrict__ v,
    float* __restrict__ bij, float* __restrict__ cbuf) {
  int tid = blockIdx.x * 256 + threadIdx.x;
  int b = tid / 1152;
  int p = tid - b * 1152;
  float br[10];
  float* bp = &bij[(size_t)tid * 10];
#pragma unroll
  for (int q = 0; q < 10; ++q) {
    const ushort_t* ub = &uh[(size_t)((b * 10 + q) * 1152 + p) * 16];
    short8 u0 = *(const short8*)ub;
    short8 u1 = *(const short8*)(ub + 8);
    const float4* v4 = reinterpret_cast<const float4*>(&v[(b * 10 + q) * 16]);
    float4 b0 = v4[0], b1 = v4[1], b2 = v4[2], b3 = v4[3];
    float d = bf2f((ushort_t)u0[0]) * b0.x + bf2f((ushort_t)u0[1]) * b0.y
            + bf2f((ushort_t)u0[2]) * b0.z + bf2f((ushort_t)u0[3]) * b0.w
            + bf2f((ushort_t)u0[4]) * b1.x + bf2f((ushort_t)u0[5]) * b1.y
            + bf2f((ushort_t)u0[6]) * b1.z + bf2f((ushort_t)u0[7]) * b1.w
            + bf2f((ushort_t)u1[0]) * b2.x + bf2f((ushort_t)u1[1]) * b2.y
            + bf2f((ushort_t)u1[2]) * b2.z + bf2f((ushort_t)u1[3]) * b2.w
            + bf2f((ushort_t)u1[4]) * b3.x + bf2f((ushort_t)u1[5]) * b3.y
            + bf2f((ushort_t)u1[6]) * b3.z + bf2f((ushort_t)u1[7]) * b3.w;
    br[q] = (FIRST ? 0.f : bp[q]) + d;
  }
  float mx = br[0];
#pragma unroll
  for (int q = 1; q < 10; ++q) mx = fmaxf(mx, br[q]);
  float den = 0.f;
  float ex[10];
#pragma unroll
  for (int q = 0; q < 10; ++q) { ex[q] = __expf(br[q] - mx); den += ex[q]; }
  float inv = 1.f / den;
#pragma unroll
  for (int q = 0; q < 10; ++q) {
    bp[q] = br[q];
    cbuf[(size_t)(b * 10 + q) * 1152 + p] = ex[q] * inv;
  }
}

// ============ fc1+fc2 fused: mv + f1 in LDS, 256 f2 outputs =============
__global__ __launch_bounds__(256) void fc12_kernel(
    const float* __restrict__ v, const float* __restrict__ y,
    const float* __restrict__ fc1_w, const float* __restrict__ fc1_b,
    const float* __restrict__ fc2_w, const float* __restrict__ fc2_b,
    float* __restrict__ f2g) {
  int b = blockIdx.x >> 2;
  int t = threadIdx.x;
  __shared__ float mv[16];
  __shared__ float f1[512];
  if (t < 16) {
    const float* vb = &v[b * 160];
    float a = 0.f;
#pragma unroll
    for (int tt = 0; tt < 10; ++tt) a += vb[t * 10 + tt] * y[b * 10 + tt];
    mv[t] = a;
  }
  __syncthreads();
  for (int o = t; o < 512; o += 256) {
    const float4* wr = reinterpret_cast<const float4*>(&fc1_w[o * 16]);
    float4 w0 = wr[0], w1 = wr[1], w2 = wr[2], w3 = wr[3];
    f1[o] = fc1_b[o]
        + mv[0] * w0.x + mv[1] * w0.y + mv[2] * w0.z + mv[3] * w0.w
        + mv[4] * w1.x + mv[5] * w1.y + mv[6] * w1.z + mv[7] * w1.w
        + mv[8] * w2.x + mv[9] * w2.y + mv[10] * w2.z + mv[11] * w2.w
        + mv[12] * w3.x + mv[13] * w3.y + mv[14] * w3.z + mv[15] * w3.w;
  }
  __syncthreads();
  int o = (blockIdx.x & 3) * 256 + t;
  const float4* wr = reinterpret_cast<const float4*>(&fc2_w[o * 512]);
  float a = fc2_b[o];
#pragma unroll 4
  for (int k4 = 0; k4 < 128; ++k4) {
    float4 w4 = wr[k4];
    a += f1[4 * k4] * w4.x + f1[4 * k4 + 1] * w4.y + f1[4 * k4 + 2] * w4.z +
         f1[4 * k4 + 3] * w4.w;
  }
  f2g[b * 1024 + o] = a;
}

// ================= fc3 + sigmoid =================
__global__ __launch_bounds__(256) void fc3_kernel(
    const float* __restrict__ f2g, const float* __restrict__ fc3_w,
    const float* __restrict__ fc3_b, float* __restrict__ out) {
  int b = blockIdx.x >> 2;
  int oc = (blockIdx.x & 3) * 196;
  __shared__ float f2[1024];
  for (int l = threadIdx.x; l < 1024; l += 256) f2[l] = f2g[b * 1024 + l];
  __syncthreads();
  if (threadIdx.x >= 196) return;
  int o = oc + threadIdx.x;
  const float4* wr = reinterpret_cast<const float4*>(&fc3_w[o * 1024]);
  float a = fc3_b[o];
#pragma unroll 4
  for (int k4 = 0; k4 < 256; ++k4) {
    float4 w4 = wr[k4];
    a += f2[4 * k4] * w4.x + f2[4 * k4 + 1] * w4.y + f2[4 * k4 + 2] * w4.z +
         f2[4 * k4 + 3] * w4.w;
  }
  out[1280 + b * 784 + o] = 1.f / (1.f + __expf(-a));
}

extern "C" void kernel_launch(void* const* d_in, const int* in_sizes, int n_in,
                              void* d_out, int out_size, void* d_ws, size_t ws_size,
                              hipStream_t stream) {
  const float* x       = (const float*)d_in[0];
  const float* y       = (const float*)d_in[1];
  const float* conv1_w = (const float*)d_in[2];
  const float* conv1_b = (const float*)d_in[3];
  const float* caps1_w = (const float*)d_in[4];
  const float* caps1_b = (const float*)d_in[5];
  const float* W       = (const float*)d_in[6];
  const float* cbias   = (const float*)d_in[7];
  const float* fc1_w   = (const float*)d_in[8];
  const float* fc1_b   = (const float*)d_in[9];
  const float* fc2_w   = (const float*)d_in[10];
  const float* fc2_b   = (const float*)d_in[11];
  const float* fc3_w   = (const float*)d_in[12];
  const float* fc3_b   = (const float*)d_in[13];
  float* out = (float*)d_out;

  char* wsb = (char*)d_ws;
  ushort_t* h1t  = (ushort_t*)(wsb + OFFB_H1T);
  ushort_t* wt   = (ushort_t*)(wsb + OFFB_WT);
  float*    part = (float*)(wsb + OFFB_PART);
  float*    h2   = (float*)(wsb + OFFB_H2);
  ushort_t* uh   = (ushort_t*)(wsb + OFFB_UH);
  float*    bij  = (float*)(wsb + OFFB_BIJ);
  float*    c    = (float*)(wsb + OFFB_C);
  float*    v    = (float*)(wsb + OFFB_V);
  float*    f2   = (float*)(wsb + OFFB_F2);
  float*    w1t  = (float*)(wsb + OFFB_W1T);

  w1t_kernel<<<81, 256, 0, stream>>>(conv1_w, w1t);
  conv1_kernel<<<2560, 256, 0, stream>>>(x, w1t, conv1_b, h1t);
  wreorder_kernel<<<256, 256, 0, stream>>>(caps1_w, wt);
  caps1_gemm<<<576, 512, 0, stream>>>(h1t, wt, part);
  reduce_kernel<<<1152, 256, 0, stream>>>(part, caps1_b, h2);
  uhat_kernel<<<1440, 256, 0, stream>>>(h2, W, uh);

  sv_kernel<0><<<1280, 256, 0, stream>>>(uh, c, cbias, v, out);
  agree_kernel<true><<<576, 256, 0, stream>>>(uh, v, bij, c);
  sv_kernel<1><<<1280, 256, 0, stream>>>(uh, c, cbias, v, out);
  agree_kernel<false><<<576, 256, 0, stream>>>(uh, v, bij, c);
  sv_kernel<2><<<1280, 256, 0, stream>>>(uh, c, cbias, v, out);

  fc12_kernel<<<512, 256, 0, stream>>>(v, y, fc1_w, fc1_b, fc2_w, fc2_b, f2);
  fc3_kernel<<<512, 256, 0, stream>>>(f2, fc3_w, fc3_b, out);
}

// Round 16
// 317.113 us; speedup vs baseline: 1.5708x; 1.0354x over previous
//
#include <hip/hip_runtime.h>
#include <hip/hip_bf16.h>

typedef unsigned short ushort_t;
typedef __attribute__((ext_vector_type(8))) short short8;
typedef __attribute__((ext_vector_type(4))) float f32x4;

// ---------------- problem constants ----------------
// conv1: x[128,1,28,28]*w[256,1,9,9] s1 -> h1t[128,20,20,256] (NHWC bf16)
// caps1: implicit GEMM M=4608 N=256 K=81*256, split-K ci-quarter.
//        r10 tile (128x64, 8 waves) but staging via global_load_lds:
//        linear LDS slots + pre-swizzled per-lane GLOBAL source (rule #21),
//        ONE barrier per kk (was two), zero ds_writes.
// reduce: part -> h2 (float4). uhat h2-based. routing sv x3 / agree x2.
// fc1+fc2 fused. Output f32.

// ---------------- ws layout (bytes) ----------------
#define OFFB_H1T  0u           // 26,214,400
#define OFFB_WT   26214400u    // 10,616,832
#define OFFB_PART 36831232u    // 18,874,368
#define OFFB_H2   55705600u    //  4,718,592
#define OFFB_UH   60424192u    // 47,185,920
#define OFFB_BIJ  107610112u   //  5,898,240
#define OFFB_C    113508352u   //  5,898,240
#define OFFB_V    119406592u   //     81,920
#define OFFB_F2   119750656u   //    524,288
#define OFFB_W1T  120274944u   //     82,944  -> total ~120.4 MB

#define PCH ((size_t)4608 * 256)

__device__ __forceinline__ ushort_t f2bf(float f) {
  union { float f; unsigned int u; } c; c.f = f;
  unsigned int r = (c.u + 0x7FFFu + ((c.u >> 16) & 1u)) >> 16;
  return (ushort_t)r;
}
__device__ __forceinline__ float bf2f(ushort_t u) {
  union { unsigned int i; float f; } c; c.i = ((unsigned int)u) << 16;
  return c.f;
}

// ========== conv1 weight transpose: w[co][kk] -> w1t[kk][co] f32 ==========
__global__ __launch_bounds__(256) void w1t_kernel(
    const float* __restrict__ w, float* __restrict__ w1t) {
  int kk = blockIdx.x;
  int co = threadIdx.x;
  w1t[kk * 256 + co] = w[co * 81 + kk];
}

// ================= conv1 + relu -> NHWC bf16 =================
__global__ __launch_bounds__(256) void conv1_kernel(
    const float* __restrict__ x, const float* __restrict__ w1t,
    const float* __restrict__ bias, ushort_t* __restrict__ h1t) {
  int blk = blockIdx.x;
  int b = blk / 20, oy = blk % 20;
  int co = threadIdx.x;
  __shared__ float xs[252];
  for (int l = co; l < 252; l += 256)
    xs[l] = x[b * 784 + (oy + l / 28) * 28 + (l % 28)];
  __syncthreads();
  float bs = bias[co];
  float acc[20];
#pragma unroll
  for (int i = 0; i < 20; ++i) acc[i] = bs;
  for (int ky = 0; ky < 9; ++ky) {
    float xr[28];
#pragma unroll
    for (int i = 0; i < 28; ++i) xr[i] = xs[ky * 28 + i];
    float wk[9];
#pragma unroll
    for (int kx = 0; kx < 9; ++kx) wk[kx] = w1t[(ky * 9 + kx) * 256 + co];
#pragma unroll
    for (int kx = 0; kx < 9; ++kx)
#pragma unroll
      for (int ox = 0; ox < 20; ++ox) acc[ox] += wk[kx] * xr[ox + kx];
  }
  int xb = (b * 20 + oy) * 20;
#pragma unroll
  for (int ox = 0; ox < 20; ++ox)
    h1t[(xb + ox) * 256 + co] = f2bf(fmaxf(acc[ox], 0.f));
}

// ========== caps1 weight reorder: w[co][ci][kk] -> wt[kk][co][ci] bf16 =====
__global__ __launch_bounds__(256) void wreorder_kernel(
    const float* __restrict__ w, ushort_t* __restrict__ wt) {
  int co = blockIdx.x;
  __shared__ ushort_t wl[256 * 82];
  int t = threadIdx.x;
  const float* src = w + (size_t)co * 20736;
  for (int e = t; e < 20736; e += 256) {
    int ci = e / 81, kk = e - ci * 81;
    wl[ci * 82 + kk] = f2bf(src[e]);
  }
  __syncthreads();
  for (int kk = 0; kk < 81; ++kk)
    wt[((size_t)kk * 256 + co) * 256 + t] = wl[t * 82 + kk];
}

// ====== caps1: r10 tile + global_load_lds staging (1 barrier/kk) ======
__global__ __launch_bounds__(512) void caps1_gemm(
    const ushort_t* __restrict__ h1t, const ushort_t* __restrict__ wt,
    float* __restrict__ part) {
  int lb = (blockIdx.x & 7) * 72 + (blockIdx.x >> 3);
  int chunk = lb / 144;
  int tile = lb - chunk * 144;
  int gm0 = (tile >> 2) * 128;
  int gn0 = (tile & 3) * 64;
  int ci0 = chunk << 6;
  int t = threadIdx.x;
  int wave = t >> 6, lane = t & 63;
  int wm = (wave >> 1) * 32, wn = (wave & 1) * 32;
  int lr = lane & 15, lg = lane >> 4;

  __shared__ __align__(16) ushort_t As[2][128 * 64];
  __shared__ __align__(16) ushort_t Bs[2][64 * 64];

  // ---- staging: linear LDS slots; XOR swizzle applied to GLOBAL source ----
  // A: 1024 slots x 16B; thread t owns slots t and t+512.
  // slot s -> row r = s>>3, lds granule s&7, SRC granule (s&7)^(r&7).
  const ushort_t* asrc0;
  const ushort_t* asrc1;
  const ushort_t* bsrc;
  {
    int s = t;
    int r = s >> 3, g = (s & 7) ^ (r & 7);
    int am = gm0 + r;
    int ab_ = am / 36, pos = am - ab_ * 36;
    int oy = pos / 6, ox = pos - oy * 6;
    asrc0 = h1t + ((ab_ * 20 + 2 * oy) * 20 + 2 * ox) * 256 + ci0 + g * 8;
  }
  {
    int s = t + 512;
    int r = s >> 3, g = (s & 7) ^ (r & 7);
    int am = gm0 + r;
    int ab_ = am / 36, pos = am - ab_ * 36;
    int oy = pos / 6, ox = pos - oy * 6;
    asrc1 = h1t + ((ab_ * 20 + 2 * oy) * 20 + 2 * ox) * 256 + ci0 + g * 8;
  }
  {
    int r = t >> 3, g = (t & 7) ^ (r & 7);
    bsrc = wt + (size_t)(gn0 + r) * 256 + ci0 + g * 8;
  }

#define STAGE(bf, kkv)                                                       \
  {                                                                          \
    int ky_ = (kkv) / 9, kx_ = (kkv)-ky_ * 9;                                \
    int aoff_ = (ky_ * 20 + kx_) * 256;                                      \
    size_t boff_ = (size_t)(kkv)*65536;                                      \
    __builtin_amdgcn_global_load_lds(                                        \
        reinterpret_cast<const unsigned int*>(asrc0 + aoff_),                \
        reinterpret_cast<unsigned int*>(&As[bf][t * 8]), 16, 0, 0);          \
    __builtin_amdgcn_global_load_lds(                                        \
        reinterpret_cast<const unsigned int*>(asrc1 + aoff_),                \
        reinterpret_cast<unsigned int*>(&As[bf][(t + 512) * 8]), 16, 0, 0);  \
    __builtin_amdgcn_global_load_lds(                                        \
        reinterpret_cast<const unsigned int*>(bsrc + boff_),                 \
        reinterpret_cast<unsigned int*>(&Bs[bf][t * 8]), 16, 0, 0);          \
  }

  // fragment-read swizzled slots (unchanged, layout identical to r15)
  int lx = lr & 7;
  int sl0 = ((0 * 4 + lg) ^ lx) * 8;
  int sl1 = ((1 * 4 + lg) ^ lx) * 8;

  f32x4 acc[2][2];
#pragma unroll
  for (int i = 0; i < 2; ++i)
#pragma unroll
    for (int j = 0; j < 2; ++j)
#pragma unroll
      for (int e = 0; e < 4; ++e) acc[i][j][e] = 0.f;

  STAGE(0, 0);
  __syncthreads();  // compiler drains vmcnt(0) before barrier

  int buf = 0;
  for (int kk = 0; kk < 81; ++kk) {
    if (kk + 1 < 81) STAGE(buf ^ 1, kk + 1);  // in flight under compute
    short8 af[2][2], bfr[2][2];
#pragma unroll
    for (int mf = 0; mf < 2; ++mf) {
      int ra = (wm + mf * 16 + lr) * 64;
      af[mf][0] = *(const short8*)&As[buf][ra + sl0];
      af[mf][1] = *(const short8*)&As[buf][ra + sl1];
    }
#pragma unroll
    for (int nf = 0; nf < 2; ++nf) {
      int rb = (wn + nf * 16 + lr) * 64;
      bfr[nf][0] = *(const short8*)&Bs[buf][rb + sl0];
      bfr[nf][1] = *(const short8*)&Bs[buf][rb + sl1];
    }
#pragma unroll
    for (int kh = 0; kh < 2; ++kh)
#pragma unroll
      for (int mf = 0; mf < 2; ++mf)
#pragma unroll
        for (int nf = 0; nf < 2; ++nf)
          acc[mf][nf] = __builtin_amdgcn_mfma_f32_16x16x32_bf16(
              af[mf][kh], bfr[nf][kh], acc[mf][nf], 0, 0, 0);
    __syncthreads();  // single barrier per kk: drains prefetch + read fence
    buf ^= 1;
  }
#undef STAGE

  float* pbase = part + (size_t)chunk * PCH;
#pragma unroll
  for (int mf = 0; mf < 2; ++mf)
#pragma unroll
    for (int nf = 0; nf < 2; ++nf) {
      int nn = gn0 + wn + nf * 16 + lr;
#pragma unroll
      for (int reg = 0; reg < 4; ++reg) {
        int mm = gm0 + wm + mf * 16 + lg * 4 + reg;
        pbase[(size_t)mm * 256 + nn] = acc[mf][nf][reg];
      }
    }
}

// ==== reduce (float4): h2[m][n] = relu(sum_c part[c][m][n] + bias[n]) =====
__global__ __launch_bounds__(256) void reduce_kernel(
    const float* __restrict__ part, const float* __restrict__ bias,
    float* __restrict__ h2) {
  int tid = blockIdx.x * 256 + threadIdx.x;
  size_t o = (size_t)tid * 4;
  int n0 = (int)(o & 255);
  float4 s0 = *(const float4*)&part[o];
  float4 s1 = *(const float4*)&part[o + PCH];
  float4 s2 = *(const float4*)&part[o + 2 * PCH];
  float4 s3 = *(const float4*)&part[o + 3 * PCH];
  float4 bv = *(const float4*)&bias[n0];
  float4 r;
  r.x = fmaxf(s0.x + s1.x + s2.x + s3.x + bv.x, 0.f);
  r.y = fmaxf(s0.y + s1.y + s2.y + s3.y + bv.y, 0.f);
  r.z = fmaxf(s0.z + s1.z + s2.z + s3.z + bv.z, 0.f);
  r.w = fmaxf(s0.w + s1.w + s2.w + s3.w + bv.w, 0.f);
  *(float4*)&h2[o] = r;
}

// ================= u_hat materialize (h2-based, verified r7) ============
__global__ __launch_bounds__(256) void uhat_kernel(
    const float* __restrict__ h2, const float* __restrict__ W,
    ushort_t* __restrict__ uh) {
  int blk = blockIdx.x;
  int bh = blk & 1;
  int qpc = blk >> 1;
  int q = qpc / 72;
  int pc = qpc - q * 72;
  int p0 = pc * 16;
  int b0 = bh * 64;
  __shared__ float Wl[16][132];
  __shared__ float xl[64][16][9];
  int t = threadIdx.x;
#pragma unroll
  for (int it = 0; it < 2; ++it) {
    int idx = t * 2 + it;
    int row = idx >> 5;
    int c4 = idx & 31;
    float4 vv = *(reinterpret_cast<const float4*>(
        &W[(size_t)((p0 + row) * 10 + q) * 128]) + c4);
    Wl[row][c4 * 4 + 0] = vv.x;
    Wl[row][c4 * 4 + 1] = vv.y;
    Wl[row][c4 * 4 + 2] = vv.z;
    Wl[row][c4 * 4 + 3] = vv.w;
  }
  for (int j = 0; j < 32; ++j) {
    int e = t + 256 * j;
    int b_l = e >> 7;
    int rem = e & 127;
    int i = rem >> 3, n = rem & 7;
    int f = (p0 + i) * 80 + q * 8 + n;
    xl[b_l][i][n] = h2[((size_t)(b0 + b_l) * 36 + (f % 36)) * 256 + (f / 360)];
  }
  __syncthreads();
  int p_l = t & 15;
  int b_ll = t >> 4;
  const float* wr = &Wl[p_l][0];
#pragma unroll
  for (int k = 0; k < 4; ++k) {
    int b_l = b_ll + 16 * k;
    float xv[8];
#pragma unroll
    for (int n = 0; n < 8; ++n) xv[n] = xl[b_l][p_l][n];
    short8 o0, o1;
#pragma unroll
    for (int a = 0; a < 8; ++a) {
      float ue = 0.f, uo = 0.f;
#pragma unroll
      for (int n = 0; n < 8; ++n) {
        ue += wr[a * 16 + n] * xv[n];
        uo += wr[a * 16 + 8 + n] * xv[n];
      }
      if (a < 4) { o0[2 * a] = (short)f2bf(ue); o0[2 * a + 1] = (short)f2bf(uo); }
      else { o1[2 * (a - 4)] = (short)f2bf(ue); o1[2 * (a - 4) + 1] = (short)f2bf(uo); }
    }
    size_t dst = ((size_t)((b0 + b_l) * 10 + q) * 1152 + p0 + p_l) * 16;
    *(short8*)&uh[dst] = o0;
    *(short8*)&uh[dst + 8] = o1;
  }
}

// ================= sv: weighted sum + squash (4 waves) =================
template <int MODE>
__global__ __launch_bounds__(256) void sv_kernel(
    const ushort_t* __restrict__ uh, const float* __restrict__ cbuf,
    const float* __restrict__ caps_bias, float* __restrict__ v,
    float* __restrict__ out) {
  int bq = blockIdx.x;
  int q = bq % 10;
  int t = threadIdx.x;
  const ushort_t* ub = &uh[(size_t)bq * 1152 * 16];
  const float* cb = &cbuf[(size_t)bq * 1152];
  float s[16];
#pragma unroll
  for (int m = 0; m < 16; ++m) s[m] = 0.f;
  for (int p = t; p < 1152; p += 256) {
    short8 u0 = *(const short8*)&ub[p * 16];
    short8 u1 = *(const short8*)&ub[p * 16 + 8];
    float c = (MODE == 0) ? 0.1f : cb[p];
#pragma unroll
    for (int m = 0; m < 8; ++m) s[m] += c * bf2f((ushort_t)u0[m]);
#pragma unroll
    for (int m = 0; m < 8; ++m) s[8 + m] += c * bf2f((ushort_t)u1[m]);
  }
  __shared__ float red[4][16];
#pragma unroll
  for (int m = 0; m < 16; ++m) {
    float val = s[m];
#pragma unroll
    for (int off = 32; off > 0; off >>= 1) val += __shfl_down(val, off);
    if ((t & 63) == 0) red[t >> 6][m] = val;
  }
  __syncthreads();
  if (t == 0) {
    float sq = 0.f;
    float sj[16];
#pragma unroll
    for (int m = 0; m < 16; ++m) {
      sj[m] = red[0][m] + red[1][m] + red[2][m] + red[3][m] +
              caps_bias[q * 16 + m];
      sq += sj[m] * sj[m];
    }
    float coef = (sq / (1.f + sq)) * rsqrtf(sq + 1e-9f);
    float vl2 = 0.f;
#pragma unroll
    for (int m = 0; m < 16; ++m) {
      float vv = coef * sj[m];
      v[bq * 16 + m] = vv;
      vl2 += vv * vv;
    }
    if (MODE == 2) out[bq] = sqrtf(vl2 + 1e-9f);
  }
}

// ======== agree: d=u.v, bij update, fused softmax -> c ========
template <bool FIRST>
__global__ __launch_bounds__(256) void agree_kernel(
    const ushort_t* __restrict__ uh, const float* __restrict__ v,
    float* __restrict__ bij, float* __restrict__ cbuf) {
  int tid = blockIdx.x * 256 + threadIdx.x;
  int b = tid / 1152;
  int p = tid - b * 1152;
  float br[10];
  float* bp = &bij[(size_t)tid * 10];
#pragma unroll
  for (int q = 0; q < 10; ++q) {
    const ushort_t* ub = &uh[(size_t)((b * 10 + q) * 1152 + p) * 16];
    short8 u0 = *(const short8*)ub;
    short8 u1 = *(const short8*)(ub + 8);
    const float4* v4 = reinterpret_cast<const float4*>(&v[(b * 10 + q) * 16]);
    float4 b0 = v4[0], b1 = v4[1], b2 = v4[2], b3 = v4[3];
    float d = bf2f((ushort_t)u0[0]) * b0.x + bf2f((ushort_t)u0[1]) * b0.y
            + bf2f((ushort_t)u0[2]) * b0.z + bf2f((ushort_t)u0[3]) * b0.w
            + bf2f((ushort_t)u0[4]) * b1.x + bf2f((ushort_t)u0[5]) * b1.y
            + bf2f((ushort_t)u0[6]) * b1.z + bf2f((ushort_t)u0[7]) * b1.w
            + bf2f((ushort_t)u1[0]) * b2.x + bf2f((ushort_t)u1[1]) * b2.y
            + bf2f((ushort_t)u1[2]) * b2.z + bf2f((ushort_t)u1[3]) * b2.w
            + bf2f((ushort_t)u1[4]) * b3.x + bf2f((ushort_t)u1[5]) * b3.y
            + bf2f((ushort_t)u1[6]) * b3.z + bf2f((ushort_t)u1[7]) * b3.w;
    br[q] = (FIRST ? 0.f : bp[q]) + d;
  }
  float mx = br[0];
#pragma unroll
  for (int q = 1; q < 10; ++q) mx = fmaxf(mx, br[q]);
  float den = 0.f;
  float ex[10];
#pragma unroll
  for (int q = 0; q < 10; ++q) { ex[q] = __expf(br[q] - mx); den += ex[q]; }
  float inv = 1.f / den;
#pragma unroll
  for (int q = 0; q < 10; ++q) {
    bp[q] = br[q];
    cbuf[(size_t)(b * 10 + q) * 1152 + p] = ex[q] * inv;
  }
}

// ============ fc1+fc2 fused: mv + f1 in LDS, 256 f2 outputs =============
__global__ __launch_bounds__(256) void fc12_kernel(
    const float* __restrict__ v, const float* __restrict__ y,
    const float* __restrict__ fc1_w, const float* __restrict__ fc1_b,
    const float* __restrict__ fc2_w, const float* __restrict__ fc2_b,
    float* __restrict__ f2g) {
  int b = blockIdx.x >> 2;
  int t = threadIdx.x;
  __shared__ float mv[16];
  __shared__ float f1[512];
  if (t < 16) {
    const float* vb = &v[b * 160];
    float a = 0.f;
#pragma unroll
    for (int tt = 0; tt < 10; ++tt) a += vb[t * 10 + tt] * y[b * 10 + tt];
    mv[t] = a;
  }
  __syncthreads();
  for (int o = t; o < 512; o += 256) {
    const float4* wr = reinterpret_cast<const float4*>(&fc1_w[o * 16]);
    float4 w0 = wr[0], w1 = wr[1], w2 = wr[2], w3 = wr[3];
    f1[o] = fc1_b[o]
        + mv[0] * w0.x + mv[1] * w0.y + mv[2] * w0.z + mv[3] * w0.w
        + mv[4] * w1.x + mv[5] * w1.y + mv[6] * w1.z + mv[7] * w1.w
        + mv[8] * w2.x + mv[9] * w2.y + mv[10] * w2.z + mv[11] * w2.w
        + mv[12] * w3.x + mv[13] * w3.y + mv[14] * w3.z + mv[15] * w3.w;
  }
  __syncthreads();
  int o = (blockIdx.x & 3) * 256 + t;
  const float4* wr = reinterpret_cast<const float4*>(&fc2_w[o * 512]);
  float a = fc2_b[o];
#pragma unroll 4
  for (int k4 = 0; k4 < 128; ++k4) {
    float4 w4 = wr[k4];
    a += f1[4 * k4] * w4.x + f1[4 * k4 + 1] * w4.y + f1[4 * k4 + 2] * w4.z +
         f1[4 * k4 + 3] * w4.w;
  }
  f2g[b * 1024 + o] = a;
}

// ================= fc3 + sigmoid =================
__global__ __launch_bounds__(256) void fc3_kernel(
    const float* __restrict__ f2g, const float* __restrict__ fc3_w,
    const float* __restrict__ fc3_b, float* __restrict__ out) {
  int b = blockIdx.x >> 2;
  int oc = (blockIdx.x & 3) * 196;
  __shared__ float f2[1024];
  for (int l = threadIdx.x; l < 1024; l += 256) f2[l] = f2g[b * 1024 + l];
  __syncthreads();
  if (threadIdx.x >= 196) return;
  int o = oc + threadIdx.x;
  const float4* wr = reinterpret_cast<const float4*>(&fc3_w[o * 1024]);
  float a = fc3_b[o];
#pragma unroll 4
  for (int k4 = 0; k4 < 256; ++k4) {
    float4 w4 = wr[k4];
    a += f2[4 * k4] * w4.x + f2[4 * k4 + 1] * w4.y + f2[4 * k4 + 2] * w4.z +
         f2[4 * k4 + 3] * w4.w;
  }
  out[1280 + b * 784 + o] = 1.f / (1.f + __expf(-a));
}

extern "C" void kernel_launch(void* const* d_in, const int* in_sizes, int n_in,
                              void* d_out, int out_size, void* d_ws, size_t ws_size,
                              hipStream_t stream) {
  const float* x       = (const float*)d_in[0];
  const float* y       = (const float*)d_in[1];
  const float* conv1_w = (const float*)d_in[2];
  const float* conv1_b = (const float*)d_in[3];
  const float* caps1_w = (const float*)d_in[4];
  const float* caps1_b = (const float*)d_in[5];
  const float* W       = (const float*)d_in[6];
  const float* cbias   = (const float*)d_in[7];
  const float* fc1_w   = (const float*)d_in[8];
  const float* fc1_b   = (const float*)d_in[9];
  const float* fc2_w   = (const float*)d_in[10];
  const float* fc2_b   = (const float*)d_in[11];
  const float* fc3_w   = (const float*)d_in[12];
  const float* fc3_b   = (const float*)d_in[13];
  float* out = (float*)d_out;

  char* wsb = (char*)d_ws;
  ushort_t* h1t  = (ushort_t*)(wsb + OFFB_H1T);
  ushort_t* wt   = (ushort_t*)(wsb + OFFB_WT);
  float*    part = (float*)(wsb + OFFB_PART);
  float*    h2   = (float*)(wsb + OFFB_H2);
  ushort_t* uh   = (ushort_t*)(wsb + OFFB_UH);
  float*    bij  = (float*)(wsb + OFFB_BIJ);
  float*    c    = (float*)(wsb + OFFB_C);
  float*    v    = (float*)(wsb + OFFB_V);
  float*    f2   = (float*)(wsb + OFFB_F2);
  float*    w1t  = (float*)(wsb + OFFB_W1T);

  w1t_kernel<<<81, 256, 0, stream>>>(conv1_w, w1t);
  conv1_kernel<<<2560, 256, 0, stream>>>(x, w1t, conv1_b, h1t);
  wreorder_kernel<<<256, 256, 0, stream>>>(caps1_w, wt);
  caps1_gemm<<<576, 512, 0, stream>>>(h1t, wt, part);
  reduce_kernel<<<1152, 256, 0, stream>>>(part, caps1_b, h2);
  uhat_kernel<<<1440, 256, 0, stream>>>(h2, W, uh);

  sv_kernel<0><<<1280, 256, 0, stream>>>(uh, c, cbias, v, out);
  agree_kernel<true><<<576, 256, 0, stream>>>(uh, v, bij, c);
  sv_kernel<1><<<1280, 256, 0, stream>>>(uh, c, cbias, v, out);
  agree_kernel<false><<<576, 256, 0, stream>>>(uh, v, bij, c);
  sv_kernel<2><<<1280, 256, 0, stream>>>(uh, c, cbias, v, out);

  fc12_kernel<<<512, 256, 0, stream>>>(v, y, fc1_w, fc1_b, fc2_w, fc2_b, f2);
  fc3_kernel<<<512, 256, 0, stream>>>(f2, fc3_w, fc3_b, out);
}